// Round 3
// baseline (459.352 us; speedup 1.0000x reference)
//
#include <hip/hip_runtime.h>

// CubeSpherePadding2D, p=1.  Input [16,64,6,96,96] f32 -> output [16,64,6,98,98].
// Round 5: homogeneous-wave split.
//   Round-4 post-mortem: every wave spanned ~2.6 output rows, so every wave
//   executed the divergent boundary slow path (scattered table loads + gathers,
//   ~300 extra cy/wave). Fix: block-level split of the index space.
//     - blocks [0, 52992): pure-interior groups, branch-free:
//       1 misaligned 16B read + 1 aligned float4 store, no divergence.
//     - blocks [52992, 57624): the 193 boundary groups per face (closed-form
//       enumeration, identical for every face), verified gather path, all
//       lanes doing useful work.

#define BC_TOTAL 1024
#define NF 6
#define HH 96
#define HP 98
#define IN_FACE (HH * HH)     // 9216
#define OUT_FACE (HP * HP)    // 9604
#define NFACES (BC_TOTAL * NF)                 // 6144

// Per face: 2401 aligned float4 groups; 2208 pure-interior + 193 boundary.
#define INT_PER_FACE 2208
#define BND_PER_FACE 193
#define NINT (NFACES * INT_PER_FACE)           // 13,565,952
#define NBND (NFACES * BND_PER_FACE)           //  1,185,792
#define INT_BLOCKS (NINT / 256)                // 52,992 exact
#define BND_BLOCKS (NBND / 256)                //  4,632 exact

// edge_tab[f*4 + edge] = {sf, br, kr, bc, kc}
// edge: 0=top(R==0), 1=bottom(R==97), 2=left(C==0), 3=right(C==97)
// t = C-1 for top/bottom, R-1 for left/right; src = I[sf][br+kr*t][bc+kc*t]
__constant__ short edge_tab[24][5] = {
    {4, 95, 0, 0, 1},  {5, 0, 0, 0, 1},   {3, 0, 1, 95, 0},  {1, 0, 1, 0, 0},
    {4, 95, -1, 95, 0},{5, 0, 1, 95, 0},  {0, 0, 1, 95, 0},  {2, 0, 1, 0, 0},
    {4, 0, 0, 95, -1}, {5, 95, 0, 95, -1},{1, 0, 1, 95, 0},  {3, 0, 1, 0, 0},
    {4, 0, 1, 0, 0},   {5, 95, -1, 0, 0}, {2, 0, 1, 95, 0},  {0, 0, 1, 0, 0},
    {2, 0, 0, 95, -1}, {0, 0, 0, 0, 1},   {3, 0, 0, 0, 1},   {1, 0, 0, 95, -1},
    {0, 95, 0, 0, 1},  {2, 95, 0, 95, -1},{3, 95, 0, 95, -1},{1, 95, 0, 0, 1},
};

// corner_tab[(f-4)*4 + cid] = {sf, sr, sc}; cid = (R==97)*2 + (C==97)
__constant__ short corner_tab[8][3] = {
    {3, 0, 0},  {1, 0, 95},  {3, 0, 95},  {1, 0, 0},
    {3, 95, 95},{1, 95, 0},  {3, 95, 0},  {1, 95, 95},
};

__device__ __forceinline__ float cube_val(const float* __restrict__ bcin,
                                          unsigned f, unsigned R, unsigned C) {
    unsigned r = R - 1u;   // wraps to huge for R==0
    unsigned c = C - 1u;
    bool rIn = r < (unsigned)HH;
    bool cIn = c < (unsigned)HH;

    if (rIn & cIn) {
        return bcin[f * IN_FACE + r * HH + c];
    }
    if (rIn ^ cIn) {
        // edge (non-corner)
        int edge, t;
        if (!rIn) { edge = (R == 0u) ? 0 : 1; t = (int)c; }
        else      { edge = (C == 0u) ? 2 : 3; t = (int)r; }
        const short* ed = edge_tab[f * 4 + edge];
        int sr = (int)ed[1] + (int)ed[2] * t;
        int sc = (int)ed[3] + (int)ed[4] * t;
        return bcin[(unsigned)ed[0] * IN_FACE + (unsigned)sr * HH + (unsigned)sc];
    }
    // corner (both out of range)
    if (f < 4u) return 0.0f;
    int cid = ((R == 97u) ? 2 : 0) + ((C == 97u) ? 1 : 0);
    const short* ed = corner_tab[(f - 4u) * 4 + cid];
    return bcin[(unsigned)ed[0] * IN_FACE + (unsigned)ed[1] * HH + (unsigned)ed[2]];
}

__global__ __launch_bounds__(256) void pad_split_kernel(
    const float* __restrict__ in, float* __restrict__ out) {

    if (blockIdx.x < (unsigned)INT_BLOCKS) {
        // ---------------- pure interior: branch-free, no divergence --------
        unsigned i = blockIdx.x * 256u + threadIdx.x;    // < NINT exactly
        unsigned g    = i % 23u;           // group-in-row, 23 per row
        unsigned rest = i / 23u;
        unsigned rr   = rest % 96u;        // 0..95
        unsigned t2   = rest / 96u;        // face linear id (bc*6+f)
        unsigned r    = rr + 1u;           // out row 1..96
        // aligned group start: C0 == 0 mod 4 on even rows, 2 mod 4 on odd rows
        unsigned C0   = ((r & 1u) ? 2u : 4u) + 4u * g;   // cols C0..C0+3 in [1,96]

        const float* src = in + (size_t)t2 * IN_FACE + (r - 1u) * HH + (C0 - 1u);
        float4 v;
        __builtin_memcpy(&v, src, 16);     // 4B-aligned 16B read

        *(float4*)(out + (size_t)t2 * OUT_FACE + r * HP + C0) = v;   // aligned
        return;
    }

    // ---------------- boundary groups: 193 per face, closed-form ----------
    unsigned j  = (blockIdx.x - (unsigned)INT_BLOCKS) * 256u + threadIdx.x;
    unsigned b  = j % (unsigned)BND_PER_FACE;
    unsigned t2 = j / (unsigned)BND_PER_FACE;

    unsigned k;   // group index within face, o = 4k
    if (b < 25u) {
        k = b;                       // row 0: o = 0..96
    } else if (b < 49u) {
        k = 2377u + (b - 25u);       // row 97: o = 9508..9600
    } else {
        // row pairs p=0..47: (r=2p+1, C0=94), (r=2p+2, C0=0), (r=2p+2, C0=96)
        unsigned c2 = b - 49u;
        unsigned p  = c2 / 3u;
        unsigned q  = c2 - 3u * p;
        k = 49u * p + (q == 0u ? 48u : (q == 1u ? 49u : 73u));
    }

    unsigned o  = 4u * k;
    unsigned R0 = o / (unsigned)HP;
    unsigned C0 = o - R0 * (unsigned)HP;
    unsigned f  = t2 % (unsigned)NF;
    const float* bcin = in + (size_t)(t2 - f) * IN_FACE;   // face 0 of this bc

    float vv[4];
    #pragma unroll
    for (int jj = 0; jj < 4; ++jj) {
        unsigned C = C0 + (unsigned)jj;
        unsigned R = R0;
        if (C >= (unsigned)HP) { C -= (unsigned)HP; R += 1u; }   // row crossing
        vv[jj] = cube_val(bcin, f, R, C);
    }
    float4 v;
    v.x = vv[0]; v.y = vv[1]; v.z = vv[2]; v.w = vv[3];
    *(float4*)(out + (size_t)t2 * OUT_FACE + o) = v;             // aligned
}

extern "C" void kernel_launch(void* const* d_in, const int* in_sizes, int n_in,
                              void* d_out, int out_size, void* d_ws, size_t ws_size,
                              hipStream_t stream) {
    const float* in = (const float*)d_in[0];
    float* out = (float*)d_out;

    hipLaunchKernelGGL(pad_split_kernel, dim3(INT_BLOCKS + BND_BLOCKS), dim3(256),
                       0, stream, in, out);
}

// Round 4
// 448.893 us; speedup vs baseline: 1.0233x; 1.0233x over previous
//
#include <hip/hip_runtime.h>

// CubeSpherePadding2D, p=1.  Input [16,64,6,96,96] f32 -> output [16,64,6,98,98].
// Round 6: persistent-ish blocks, deep per-wave memory pipeline.
//   Round-5 post-mortem: all prior variants (57,624 one-shot workgroups, one
//   load + one dependent store per wave) pinned at 2.6-2.8 TB/s with wave
//   lifetime ~12K cycles -- queue-saturated, zero per-wave ILP (Guideline 11
//   anti-pattern).  Also the interior/boundary block split cost +113 MB of
//   partial-line RMW traffic because the two phases ran ~100us apart.
//   Fix: 2048 blocks x 256 threads; block b owns faces [3b, 3b+3).
//     per face: boundary pass (threads 0..192, verified gather tables),
//     then 8+tail unrolled interior loop (27 indep load/store pairs/thread,
//     unroll 4 -> multiple 16B loads in flight per wave).
//   Boundary and interior of a face are written by the SAME block within ~us,
//   so partial cache lines merge in L2 instead of RMW-ing through HBM.

#define BC_TOTAL 1024
#define NF 6
#define HH 96
#define HP 98
#define IN_FACE (HH * HH)     // 9216
#define OUT_FACE (HP * HP)    // 9604
#define NFACES (BC_TOTAL * NF)    // 6144 = 2048 * 3
#define NBLOCKS 2048
#define FACES_PER_BLOCK 3
#define INT_PER_FACE 2208         // 96 rows x 23 groups (cols 2..93 / 4..95)
#define BND_PER_FACE 193

// edge_tab[f*4 + edge] = {sf, br, kr, bc, kc}
// edge: 0=top(R==0), 1=bottom(R==97), 2=left(C==0), 3=right(C==97)
// t = C-1 for top/bottom, R-1 for left/right; src = I[sf][br+kr*t][bc+kc*t]
__constant__ short edge_tab[24][5] = {
    {4, 95, 0, 0, 1},  {5, 0, 0, 0, 1},   {3, 0, 1, 95, 0},  {1, 0, 1, 0, 0},
    {4, 95, -1, 95, 0},{5, 0, 1, 95, 0},  {0, 0, 1, 95, 0},  {2, 0, 1, 0, 0},
    {4, 0, 0, 95, -1}, {5, 95, 0, 95, -1},{1, 0, 1, 95, 0},  {3, 0, 1, 0, 0},
    {4, 0, 1, 0, 0},   {5, 95, -1, 0, 0}, {2, 0, 1, 95, 0},  {0, 0, 1, 0, 0},
    {2, 0, 0, 95, -1}, {0, 0, 0, 0, 1},   {3, 0, 0, 0, 1},   {1, 0, 0, 95, -1},
    {0, 95, 0, 0, 1},  {2, 95, 0, 95, -1},{3, 95, 0, 95, -1},{1, 95, 0, 0, 1},
};

// corner_tab[(f-4)*4 + cid] = {sf, sr, sc}; cid = (R==97)*2 + (C==97)
__constant__ short corner_tab[8][3] = {
    {3, 0, 0},  {1, 0, 95},  {3, 0, 95},  {1, 0, 0},
    {3, 95, 95},{1, 95, 0},  {3, 95, 0},  {1, 95, 95},
};

__device__ __forceinline__ float cube_val(const float* __restrict__ bcin,
                                          unsigned f, unsigned R, unsigned C) {
    unsigned r = R - 1u;   // wraps to huge for R==0
    unsigned c = C - 1u;
    bool rIn = r < (unsigned)HH;
    bool cIn = c < (unsigned)HH;

    if (rIn & cIn) {
        return bcin[f * IN_FACE + r * HH + c];
    }
    if (rIn ^ cIn) {
        // edge (non-corner)
        int edge, t;
        if (!rIn) { edge = (R == 0u) ? 0 : 1; t = (int)c; }
        else      { edge = (C == 0u) ? 2 : 3; t = (int)r; }
        const short* ed = edge_tab[f * 4 + edge];
        int sr = (int)ed[1] + (int)ed[2] * t;
        int sc = (int)ed[3] + (int)ed[4] * t;
        return bcin[(unsigned)ed[0] * IN_FACE + (unsigned)sr * HH + (unsigned)sc];
    }
    // corner (both out of range)
    if (f < 4u) return 0.0f;
    int cid = ((R == 97u) ? 2 : 0) + ((C == 97u) ? 1 : 0);
    const short* ed = corner_tab[(f - 4u) * 4 + cid];
    return bcin[(unsigned)ed[0] * IN_FACE + (unsigned)ed[1] * HH + (unsigned)ed[2]];
}

__global__ __launch_bounds__(256) void pad_kernel(
    const float* __restrict__ in, float* __restrict__ out) {
    const unsigned tid = threadIdx.x;
    const unsigned face0 = blockIdx.x * (unsigned)FACES_PER_BLOCK;

    for (unsigned fi = 0; fi < (unsigned)FACES_PER_BLOCK; ++fi) {
        const unsigned t2 = face0 + fi;            // face linear id (bc*6+f)
        const unsigned f  = t2 % (unsigned)NF;
        const float* __restrict__ bcin    = in  + (size_t)(t2 - f) * IN_FACE;
        const float* __restrict__ face_in = in  + (size_t)t2 * IN_FACE;
        float*       __restrict__ face_out = out + (size_t)t2 * OUT_FACE;

        // ---- boundary: 193 aligned float4 groups (verified decomposition) --
        if (tid < (unsigned)BND_PER_FACE) {
            unsigned b = tid;
            unsigned k;   // group index within face, o = 4k
            if (b < 25u) {
                k = b;                       // row 0: o = 0..96
            } else if (b < 49u) {
                k = 2377u + (b - 25u);       // row 97: o = 9508..9600
            } else {
                // row pairs p=0..47: (r=2p+1,C0=94),(r=2p+2,C0=0),(r=2p+2,C0=96)
                unsigned c2 = b - 49u;
                unsigned p  = c2 / 3u;
                unsigned q  = c2 - 3u * p;
                k = 49u * p + (q == 0u ? 48u : (q == 1u ? 49u : 73u));
            }
            unsigned o  = 4u * k;
            unsigned R0 = o / (unsigned)HP;
            unsigned C0 = o - R0 * (unsigned)HP;

            float vv[4];
            #pragma unroll
            for (int jj = 0; jj < 4; ++jj) {
                unsigned C = C0 + (unsigned)jj;
                unsigned R = R0;
                if (C >= (unsigned)HP) { C -= (unsigned)HP; R += 1u; }
                vv[jj] = cube_val(bcin, f, R, C);
            }
            float4 v;
            v.x = vv[0]; v.y = vv[1]; v.z = vv[2]; v.w = vv[3];
            *(float4*)(face_out + o) = v;
        }

        // ---- interior: 2208 groups = 8*256 + 160, unrolled for VMEM ILP ---
        #pragma unroll 4
        for (unsigned it = 0; it < 8u; ++it) {
            unsigned k  = it * 256u + tid;
            unsigned rr = k / 23u;                       // magic-mul
            unsigned g  = k - rr * 23u;
            unsigned r  = rr + 1u;                       // out row 1..96
            unsigned C0 = ((r & 1u) ? 2u : 4u) + 4u * g; // cols C0..C0+3 in [2,95]
            const float* src = face_in + (r - 1u) * HH + (C0 - 1u);
            float4 v;
            __builtin_memcpy(&v, src, 16);               // 4B-aligned 16B read
            *(float4*)(face_out + r * HP + C0) = v;      // 16B-aligned store
        }
        if (tid < 160u) {                                // tail: k = 2048..2207
            unsigned k  = 2048u + tid;
            unsigned rr = k / 23u;
            unsigned g  = k - rr * 23u;
            unsigned r  = rr + 1u;
            unsigned C0 = ((r & 1u) ? 2u : 4u) + 4u * g;
            const float* src = face_in + (r - 1u) * HH + (C0 - 1u);
            float4 v;
            __builtin_memcpy(&v, src, 16);
            *(float4*)(face_out + r * HP + C0) = v;
        }
    }
}

extern "C" void kernel_launch(void* const* d_in, const int* in_sizes, int n_in,
                              void* d_out, int out_size, void* d_ws, size_t ws_size,
                              hipStream_t stream) {
    const float* in = (const float*)d_in[0];
    float* out = (float*)d_out;

    hipLaunchKernelGGL(pad_kernel, dim3(NBLOCKS), dim3(256), 0, stream, in, out);
}